// Round 3
// baseline (556.008 us; speedup 1.0000x reference)
//
#include <hip/hip_runtime.h>
#include <stdint.h>

#define NROWS 8192
#define NCOLS 8192
#define KTOP  64
#define BLOCK 256
#define CAP   1024   // candidate buffer capacity (typ. need ~190 for N(0,1))
#define HPAD  257    // per-wave hist stride: decorrelates banks across waves

// Order-preserving float -> uint32 transform (ascending).
__device__ __forceinline__ uint32_t fkey(float f) {
    uint32_t s = __float_as_uint(f);
    return (s & 0x80000000u) ? ~s : (s | 0x80000000u);
}
__device__ __forceinline__ float finv(uint32_t u) {
    uint32_t s = (u & 0x80000000u) ? (u ^ 0x80000000u) : ~u;
    return __uint_as_float(s);
}

__global__ __launch_bounds__(BLOCK) void topk_mask_kernel(
    const float* __restrict__ x, float* __restrict__ out) {
    __shared__ uint32_t hist[4 * HPAD];       // per-wave 256-bin histograms
    __shared__ uint32_t cand_key[CAP];
    __shared__ uint32_t cand_col[CAP];
    __shared__ uint32_t wtot[4];
    __shared__ uint32_t s_selbin, s_cumab, s_cnt, s_nc, s_thr, s_eqcut;

    const int tid  = threadIdx.x;
    const int wave = tid >> 6;
    const int lane = tid & 63;
    const int row  = blockIdx.x;
    const float4* __restrict__ xrow = (const float4*)(x + (size_t)row * NCOLS);

    // ---- Load row into registers as sortable keys (32 keys/thread) ----
    uint32_t key[32];
    #pragma unroll
    for (int i = 0; i < 8; ++i) {
        float4 v = xrow[tid + i * BLOCK];
        key[i*4+0] = fkey(v.x);
        key[i*4+1] = fkey(v.y);
        key[i*4+2] = fkey(v.z);
        key[i*4+3] = fkey(v.w);
    }

    // ---- Radix narrowing: usually ONE 8-bit pass, early exit at nc<=CAP ----
    // Passes 0..3 select key bytes (descending); pass 4 (degenerate rows only)
    // selects on complemented column-high-byte so that "descending byte" ==
    // "ascending column", matching stable top_k tie-break.
    uint32_t pref = 0, himask = 0, krem = KTOP;
    uint32_t colbin = 0xFFFFFFFFu;            // sentinel: no column restriction
    uint32_t nc = 0xFFFFFFFFu;
    int p = 0;

    while (p < 5 && nc > CAP) {
        for (int t = tid; t < 4 * HPAD; t += BLOCK) hist[t] = 0;
        __syncthreads();

        const int shift = 24 - 8 * p;          // only used when p < 4
        uint32_t* myhist = &hist[wave * HPAD];
        #pragma unroll
        for (int i = 0; i < 8; ++i) {
            #pragma unroll
            for (int l = 0; l < 4; ++l) {
                uint32_t k = key[i*4+l];
                bool live = ((k & himask) == pref);
                uint32_t byte_;
                if (p < 4) {
                    byte_ = (k >> shift) & 0xFFu;
                } else {
                    uint32_t col = (uint32_t)((tid + i*BLOCK)*4 + l);
                    byte_ = (~(col >> 5)) & 0xFFu;
                }
                if (live) atomicAdd(&myhist[byte_], 1u);
            }
        }
        __syncthreads();

        // Suffix counts S_incl(b) = #keys in bins >= b, via reversed
        // wave-shuffle inclusive scan (2 barriers instead of 16).
        const uint32_t b = 255u - (uint32_t)tid;
        uint32_t v = hist[0*HPAD + b] + hist[1*HPAD + b]
                   + hist[2*HPAD + b] + hist[3*HPAD + b];
        uint32_t sc = v;
        #pragma unroll
        for (int off = 1; off < 64; off <<= 1) {
            uint32_t t = __shfl_up(sc, (unsigned)off, 64);
            if (lane >= off) sc += t;
        }
        if (lane == 63) wtot[wave] = sc;
        __syncthreads();
        uint32_t add = 0;
        #pragma unroll
        for (int w = 0; w < 4; ++w) if (w < wave) add += wtot[w];
        sc += add;                             // S_incl for bin b
        if ((sc - v) < krem && sc >= krem) {   // exactly one bin crosses
            s_selbin = b;
            s_cumab  = sc - v;
            s_cnt    = v;
        }
        __syncthreads();

        const uint32_t selbin = s_selbin;
        if (p < 4) {
            pref   |= selbin << shift;
            himask |= 0xFFu << shift;
        } else {
            colbin = selbin;
        }
        krem -= s_cumab;
        nc = s_cnt;
        ++p;
        __syncthreads();                       // hist/scalars reuse guard
    }

    // ---- Compact live candidates (typ. ~190) into LDS ----
    if (tid == 0) s_nc = 0;
    __syncthreads();
    #pragma unroll
    for (int i = 0; i < 8; ++i) {
        #pragma unroll
        for (int l = 0; l < 4; ++l) {
            uint32_t k = key[i*4+l];
            uint32_t col = (uint32_t)((tid + i*BLOCK)*4 + l);
            bool live = ((k & himask) == pref);
            if (colbin != 0xFFFFFFFFu)
                live = live && (((~(col >> 5)) & 0xFFu) == colbin);
            if (live) {
                uint32_t pos = atomicAdd(&s_nc, 1u);
                if (pos < CAP) { cand_key[pos] = k; cand_col[pos] = col; }
            }
        }
    }
    __syncthreads();

    // ---- Exact rank selection among candidates: the (krem-1)-ranked
    // element under (key desc, col asc) is the global K-th. Broadcast reads.
    const uint32_t ncand = s_nc;
    for (uint32_t c = tid; c < ncand; c += BLOCK) {
        uint32_t kc = cand_key[c], cc = cand_col[c];
        uint32_t rank = 0;
        for (uint32_t j = 0; j < ncand; ++j) {
            uint32_t kj = cand_key[j], cj = cand_col[j];
            rank += (kj > kc || (kj == kc && cj < cc)) ? 1u : 0u;
        }
        if (rank == krem - 1u) { s_thr = kc; s_eqcut = cc; }
    }
    __syncthreads();

    // ---- Output pass straight from registers ----
    const uint32_t thr = s_thr, eqcut = s_eqcut;
    float4* __restrict__ orow = (float4*)(out + (size_t)row * NCOLS);
    #pragma unroll
    for (int i = 0; i < 8; ++i) {
        uint32_t base = (uint32_t)((tid + i*BLOCK)*4);
        uint32_t k0 = key[i*4+0], k1 = key[i*4+1];
        uint32_t k2 = key[i*4+2], k3 = key[i*4+3];
        float4 o;
        o.x = (k0 > thr || (k0 == thr && base+0u <= eqcut)) ? finv(k0) : 0.0f;
        o.y = (k1 > thr || (k1 == thr && base+1u <= eqcut)) ? finv(k1) : 0.0f;
        o.z = (k2 > thr || (k2 == thr && base+2u <= eqcut)) ? finv(k2) : 0.0f;
        o.w = (k3 > thr || (k3 == thr && base+3u <= eqcut)) ? finv(k3) : 0.0f;
        orow[tid + i*BLOCK] = o;
    }
}

extern "C" void kernel_launch(void* const* d_in, const int* in_sizes, int n_in,
                              void* d_out, int out_size, void* d_ws, size_t ws_size,
                              hipStream_t stream) {
    const float* x = (const float*)d_in[0];
    float* out = (float*)d_out;
    topk_mask_kernel<<<NROWS, BLOCK, 0, stream>>>(x, out);
}